// Round 14
// baseline (1257.371 us; speedup 1.0000x reference)
//
#include <hip/hip_runtime.h>
#include <hip/hip_bf16.h>

// RITS recurrent imputation, B=1024 T=100 F=64 H=256.
// Round 19: r17 base (714us warm best; XCD-local siblings + LDS-only
// barriers; r18's neutral bank remaps reverted) + step-invariant weight
// hoist: lw_hist/lw_comb/lw_feat/lw_dh were re-read from LDS EVERY step
// (64 b128 reads in W2 + 16 in W3 of ~216 total -> W2 is LDS-pipe-bound).
// They now live in a role-shared register array wB[10] (40 VGPRs), loaded
// once from global; the four LDS arrays are deleted (LDS 130KB -> ~62KB).
// r15's spill disaster is addressed at the root: amdgpu_waves_per_eu(4,4)
// pins exactly 4 waves/SIMD (our true occupancy: 16 waves, 1 block/CU by
// LDS) -> allocator budget 128 VGPR. Frame: wfrag 48 + wB 40 + ~25 working.
// Weight VALUES bit-identical (same wsbf bf16, same fragment indices); FP
// order untouched. Kill-switch: VGPR_Count stuck at 64 or FETCH >= 300MB
// means the allocator spilled -> revert to r17.

#define Bz 1024
#define Tz 100
#define Fz 64
#define Hz 256
#define GROUPS 64
#define SIBS 4
#define RPB 16

typedef __attribute__((ext_vector_type(8))) short short8;
typedef __attribute__((ext_vector_type(4))) float floatx4;
typedef __hip_bfloat16 bf16;
typedef unsigned long long u64;

#define MFMA16(a, b, c) __builtin_amdgcn_mfma_f32_16x16x32_bf16((a), (b), (c), 0, 0, 0)

__device__ __forceinline__ float sigmf(float x) { return 1.0f / (1.0f + __expf(-x)); }
__device__ __forceinline__ float tanhfast(float x) { return 2.0f / (1.0f + __expf(-2.0f * x)) - 1.0f; }

// LDS-only barrier: full LDS visibility (lgkmcnt 0 drain) without the
// vmcnt(0) drain __syncthreads would impose. sched_barrier(0) pins all
// memory ops on both sides (rule #18 hoisting hazard).
__device__ __forceinline__ void bar_lds() {
    __builtin_amdgcn_sched_barrier(0);
    asm volatile("s_waitcnt lgkmcnt(0)" ::: "memory");
    __builtin_amdgcn_s_barrier();
    __builtin_amdgcn_sched_barrier(0);
}

// ws layout (bytes):
//   wsbf (bf16): Wdh[256x64]@0, Whist[64x256]@16384, Wfeatm[64x64]@32768,
//     Wcomb[64x128]@36864, Wp5[12*32768]@45056 ; 438272 bf16 = 876544 B
//   @876544: wdx_diag[64] f32
//   @876800: lossbuf[64*100*4] f32 (102400 B)
//   @979200: flags[64*4*4] u32, stride 16B each (16384 B)
//   @995584: pub[64][2][256][4] u64 (1 MB)
// Wp5 flat: s*32768 + w5*2048 + g*512 + l*32 + q*8 + e ; row n=g*256+w5*16+l.

__global__ void rits_convert(const float* __restrict__ Wdh, const float* __restrict__ Wdx,
                             const float* __restrict__ Whist, const float* __restrict__ Wfeat,
                             const float* __restrict__ Wcomb, const float* __restrict__ Wih,
                             const float* __restrict__ Whh, bf16* __restrict__ wsbf,
                             float* __restrict__ wdxd, unsigned int* __restrict__ flagsArr) {
    int idx = blockIdx.x * blockDim.x + threadIdx.x;
    if (idx < 4096) flagsArr[idx] = 0u;  // zero all flag lines each launch
    if (idx < 64) wdxd[idx] = Wdx[idx * 65];  // diag of W_dx
    if (idx >= 438272) return;
    float v;
    if (idx < 16384) v = Wdh[idx];
    else if (idx < 32768) v = Whist[idx - 16384];
    else if (idx < 36864) { int i = idx - 32768; v = ((i >> 6) == (i & 63)) ? 0.0f : Wfeat[i]; }
    else if (idx < 45056) v = Wcomb[idx - 36864];
    else {
        int i = idx - 45056;
        int e = i & 7, q = (i >> 3) & 3, l = (i >> 5) & 15, g = (i >> 9) & 3, w = (i >> 11) & 15;
        int s = i >> 15;
        int n = g * 256 + w * 16 + l;
        v = (s < 4) ? Wih[n * 128 + s * 32 + q * 8 + e] : Whh[n * 256 + (s - 4) * 32 + q * 8 + e];
    }
    wsbf[idx] = __float2bfloat16(v);
}

__global__ __launch_bounds__(1024)
__attribute__((amdgpu_waves_per_eu(4, 4))) void rits_main(
    const float* __restrict__ X, const float* __restrict__ Mm, const float* __restrict__ Dd,
    const float* __restrict__ b_dh, const float* __restrict__ b_dx,
    const float* __restrict__ b_hist, const float* __restrict__ b_feat,
    const float* __restrict__ b_comb, const float* __restrict__ b_ih,
    const float* __restrict__ b_hh,
    const bf16* __restrict__ Wdh, const bf16* __restrict__ Whist,
    const bf16* __restrict__ Wfeatm, const bf16* __restrict__ Wcomb,
    const bf16* __restrict__ Wp5,
    const float* __restrict__ wdxd, float* __restrict__ lossbuf,
    unsigned int* __restrict__ flags, u64* __restrict__ pub, float* __restrict__ out) {
    // ---- LDS (~62 KB after weight hoist; still 1 block/CU by grid) ----
    __shared__ __align__(16) bf16 sh_hbf[RPB * 264];   // full decayed h (bf16)
    __shared__ __align__(16) float sh_x[RPB * 64];
    __shared__ __align__(16) float sh_m[RPB * 64];
    __shared__ __align__(16) bf16 sh_dbf2[RPB * 72];   // d(t+1), staged in W2
    __shared__ __align__(16) bf16 sh_xcbf[RPB * 72];
    __shared__ __align__(16) bf16 sh_gmbf[RPB * 136];
    __shared__ __align__(16) bf16 sh_inbf[RPB * 136];
    __shared__ __align__(16) float sh_alpha[RPB * 68];
    __shared__ __align__(16) float sh_gam[RPB * 68];   // gamma_h(d_{t+1}), own cols
    __shared__ __align__(16) float sh_g[4 * 16 * 66];  // post-nonlin gates
    __shared__ __align__(16) float sh_c[64 * 16];      // c state, col-major [col][row]
    __shared__ float sh_lred[16];
    __shared__ float sh_msum[16];

    const int tid = threadIdx.x;
    const int lane = tid & 63;
    const int wid = tid >> 6;   // 0..15
    const int l16 = lane & 15;
    const int q = lane >> 4;    // 0..3
    const int j = blockIdx.x >> 6;    // sibling: owns H cols [64j, 64j+64)
    const int grp = blockIdx.x & 63;  // siblings {g,g+64,g+128,g+192} -> same XCD
    const int b0 = grp * RPB;

    // ---- state init (weights no longer staged to LDS) ----
    for (int i = tid; i < 64 * 16; i += 1024) sh_c[i] = 0.0f;
    for (int i = tid; i < RPB * 264; i += 1024) sh_hbf[i] = (bf16)0.0f;

    // ---- P5 gate-weight fragments: PERMANENT register residency ----
    const int gate = wid >> 2;  // 0..3 (i,f,g,o)
    const int ct = wid & 3;     // col-tile within sibling slice
    const int nrow = gate * 256 + j * 64 + ct * 16 + l16;
    short8 wfrag[12];
#pragma unroll
    for (int s = 0; s < 12; ++s)
        wfrag[s] = *(const short8*)(Wp5 + (size_t)s * 32768 + (j * 4 + ct) * 2048 + gate * 512 +
                                    l16 * 32 + q * 8);
    const float bgate = b_ih[nrow] + b_hh[nrow];

    // ---- step-invariant scalars (per-role) ----
    const float wdxf = wdxd[lane];
    const float bdxf = b_dx[lane];
    const int ca = wid * 16 + l16;          // alpha col (w0-3)
    const int colF = (wid - 4) * 16 + l16;  // F col (w4-7)
    const int colg = (wid - 8) * 16 + l16;  // gamma2 local col (w8-11)
    float bc2 = 0.f, bhl = 0.f, bft = 0.f, bdl = 0.f;
    if (wid < 4) bc2 = b_comb[ca];
    else if (wid < 8) { bhl = b_hist[colF]; bft = b_feat[colF]; }
    else if (wid < 12) bdl = b_dh[j * 64 + colg];

    // ---- step-invariant B-fragments: PERMANENT register residency ----
    // role-shared array: w0-3 comb[0..3]; w4-7 hist[0..7]+feat[8..9];
    // w8-11 dh[0..1]; w12-15 unused. Same bf16 values as the old LDS copies.
    short8 wB[10];
#pragma unroll
    for (int s = 0; s < 10; ++s) wB[s] = short8{0, 0, 0, 0, 0, 0, 0, 0};
    if (wid < 4) {
#pragma unroll
        for (int kb = 0; kb < 4; ++kb)
            wB[kb] = *(const short8*)(Wcomb + ca * 128 + kb * 32 + q * 8);
    } else if (wid < 8) {
#pragma unroll
        for (int kb = 0; kb < 8; ++kb)
            wB[kb] = *(const short8*)(Whist + colF * 256 + kb * 32 + q * 8);
        wB[8] = *(const short8*)(Wfeatm + colF * 64 + q * 8);
        wB[9] = *(const short8*)(Wfeatm + colF * 64 + 32 + q * 8);
    } else if (wid < 12) {
        wB[0] = *(const short8*)(Wdh + (j * 64 + colg) * 64 + q * 8);
        wB[1] = *(const short8*)(Wdh + (j * 64 + colg) * 64 + 32 + q * 8);
    }

    const size_t g0 = (size_t)(b0 + wid) * Tz * Fz + lane;
    float xv = X[g0], mv = Mm[g0], dv = Dd[g0];

    __syncthreads();  // full barrier: LDS init complete

    // ---- initial publish: zeros for t=0 (h=0 -> decayed h=0), flags=1 ----
    {
        u64* pub0 = pub + (size_t)grp * 2 * 1024;
        if (tid < 256) {
            int col = tid >> 2, qq = tid & 3;
            __hip_atomic_store(pub0 + (size_t)(j * 64 + col) * 4 + qq, 0ull, __ATOMIC_RELAXED,
                               __HIP_MEMORY_SCOPE_AGENT);
        }
        asm volatile("s_waitcnt vmcnt(0)" ::: "memory");
        if (tid < 256 && lane == 0)
            __hip_atomic_store(&flags[((grp * 4 + j) * 4 + wid) * 4], 1u, __ATOMIC_RELAXED,
                               __HIP_MEMORY_SCOPE_AGENT);
    }

    for (int t = 0; t < Tz; ++t) {
        const bool lossStep = ((t & 3) == j);
        u64* pubt = pub + ((size_t)grp * 2 + (t & 1)) * 1024;

        // ---- W0: stage x,m; gamma_x; msum; issue t+1 prefetch; poll ----
        {
            const int row = wid, f = lane;
            sh_x[row * 64 + f] = xv;
            sh_m[row * 64 + f] = mv;
            float gx = __expf(-fmaxf(dv * wdxf + bdxf, 0.0f));
            sh_gmbf[row * 136 + f] = __float2bfloat16(gx);
            bf16 mb = __float2bfloat16(mv);
            sh_gmbf[row * 136 + 64 + f] = mb;
            sh_inbf[row * 136 + 64 + f] = mb;
            if (lossStep) {  // msum only computed on the step this block consumes it
                float v0 = mv;
#pragma unroll
                for (int off = 32; off; off >>= 1) v0 += __shfl_xor(v0, off, 64);
                if (lane == 0) sh_msum[wid] = v0;
            }
        }
        if (t + 1 < Tz) {  // t+1 loads issue here; with LDS-only barriers they
            size_t g = g0 + (size_t)(t + 1) * Fz;  // float to their consumers
            xv = X[g]; mv = Mm[g]; dv = Dd[g];
        }
        if (tid < 12) {  // flags were set during remote step t-1 tail -> ~1-shot
            int sidx = tid >> 2;
            int sib = sidx + (sidx >= j);
            int w = tid & 3;
            const unsigned target = (unsigned)(t + 1);
            unsigned it = 0;
            while (__hip_atomic_load(&flags[((grp * 4 + sib) * 4 + w) * 4], __ATOMIC_RELAXED,
                                     __HIP_MEMORY_SCOPE_AGENT) < target) {
                __builtin_amdgcn_s_sleep(1);
                if (++it > (1u << 22)) break;  // liveness escape
            }
        }
        bar_lds();  // bar1

        // ---- W1: readback remote decayed-h slices -> sh_hbf ----
        if (tid < 768) {
            int sidx = tid >> 8;
            int sib = sidx + (sidx >= j);
            int c = sib * 64 + ((tid >> 2) & 63);
            int qq = tid & 3;
            u64 v = __hip_atomic_load(pubt + (size_t)c * 4 + qq, __ATOMIC_RELAXED,
                                      __HIP_MEMORY_SCOPE_AGENT);
            unsigned short* hb = (unsigned short*)sh_hbf;
#pragma unroll
            for (int r = 0; r < 4; ++r) hb[(qq * 4 + r) * 264 + c] = (unsigned short)(v >> (16 * r));
        }
        bar_lds();  // bar2

        // ---- W2: P2+xc (w4-7) | alpha (w0-3) | P5 s2-11 (all but w4-7) ----
        floatx4 acc5 = {0.f, 0.f, 0.f, 0.f};
        float xh[4];
        float l1 = 0.f, l2 = 0.f, l3 = 0.f;
        if (wid >= 4 && wid < 8) {
            floatx4 acc = {0.f, 0.f, 0.f, 0.f};
#pragma unroll
            for (int kb = 0; kb < 8; ++kb) {
                short8 a = *(const short8*)(sh_hbf + l16 * 264 + kb * 32 + q * 8);
                acc = MFMA16(a, wB[kb], acc);
            }
#pragma unroll
            for (int r = 0; r < 4; ++r) {
                int row = q * 4 + r;
                xh[r] = acc[r] + bhl;
                float xx = sh_x[row * 64 + colF], mm = sh_m[row * 64 + colF];
                l1 += fabsf(xh[r] - xx) * mm;
                float xc = mm * xx + (1.0f - mm) * xh[r];
                sh_xcbf[row * 72 + colF] = __float2bfloat16(xc);
            }
        } else {
            if (wid < 4) {
                floatx4 acca = {0.f, 0.f, 0.f, 0.f};
#pragma unroll
                for (int kb = 0; kb < 4; ++kb) {
                    short8 a = *(const short8*)(sh_gmbf + l16 * 136 + kb * 32 + q * 8);
                    acca = MFMA16(a, wB[kb], acca);
                }
#pragma unroll
                for (int r = 0; r < 4; ++r) sh_alpha[(q * 4 + r) * 68 + ca] = sigmf(acca[r] + bc2);
            }
#pragma unroll
            for (int s = 2; s < 4; ++s) {
                short8 a = *(const short8*)(sh_inbf + l16 * 136 + s * 32 + q * 8);
                acc5 = MFMA16(a, wfrag[s], acc5);
            }
#pragma unroll
            for (int s = 4; s < 12; ++s) {
                short8 a = *(const short8*)(sh_hbf + l16 * 264 + (s - 4) * 32 + q * 8);
                acc5 = MFMA16(a, wfrag[s], acc5);
            }
        }
        if (t + 1 < Tz) sh_dbf2[wid * 72 + lane] = __float2bfloat16(dv);
        bar_lds();  // bar3

        // ---- W3: P34 epilogue (w4-7) | gamma_h(d_{t+1}) (w8-11) ----
        if (wid >= 4 && wid < 8) {
            floatx4 accz = {0.f, 0.f, 0.f, 0.f};
            {
                short8 a = *(const short8*)(sh_xcbf + l16 * 72 + q * 8);
                accz = MFMA16(a, wB[8], accz);
                a = *(const short8*)(sh_xcbf + l16 * 72 + 32 + q * 8);
                accz = MFMA16(a, wB[9], accz);
            }
#pragma unroll
            for (int r = 0; r < 4; ++r) {
                int row = q * 4 + r;
                float xx = sh_x[row * 64 + colF], mm = sh_m[row * 64 + colF];
                float z = accz[r] + bft;
                l2 += fabsf(z - xx) * mm;
                float al = sh_alpha[row * 68 + colF];
                float ch = al * z + (1.0f - al) * xh[r];
                l3 += fabsf(ch - xx) * mm;
                float imp = mm * xx + (1.0f - mm) * ch;  // == c_c
                if (wid - 4 == j) out[((size_t)(b0 + row) * Tz + t) * Fz + colF] = imp;
                sh_inbf[row * 136 + colF] = __float2bfloat16(imp);
            }
            if (lossStep) {  // reduce only on the step this block publishes loss
                float v1 = l1, v2 = l2, v3 = l3;
#pragma unroll
                for (int off = 32; off; off >>= 1) {
                    v1 += __shfl_xor(v1, off, 64);
                    v2 += __shfl_xor(v2, off, 64);
                    v3 += __shfl_xor(v3, off, 64);
                }
                if (lane == 0) {
                    sh_lred[(wid - 4) * 4 + 0] = v1;
                    sh_lred[(wid - 4) * 4 + 1] = v2;
                    sh_lred[(wid - 4) * 4 + 2] = v3;
                }
            }
        } else if (wid >= 8 && wid < 12 && t + 1 < Tz) {
            short8 a0 = *(const short8*)(sh_dbf2 + l16 * 72 + q * 8);
            short8 a1 = *(const short8*)(sh_dbf2 + l16 * 72 + 32 + q * 8);
            floatx4 acc = {0.f, 0.f, 0.f, 0.f};
            acc = MFMA16(a0, wB[0], acc);
            acc = MFMA16(a1, wB[1], acc);
#pragma unroll
            for (int r = 0; r < 4; ++r)
                sh_gam[(q * 4 + r) * 68 + colg] = __expf(-fmaxf(acc[r] + bdl, 0.0f));
        }
        bar_lds();  // bar4

        // ---- W4: all 16 waves finish gates (s0,1 = c_c slots) + nonlin ----
        {
#pragma unroll
            for (int s = 0; s < 2; ++s) {
                short8 a = *(const short8*)(sh_inbf + l16 * 136 + s * 32 + q * 8);
                acc5 = MFMA16(a, wfrag[s], acc5);
            }
#pragma unroll
            for (int r = 0; r < 4; ++r) {
                float v = acc5[r] + bgate;
                float tv = (gate == 2) ? tanhfast(v) : sigmf(v);
                sh_g[(gate * 16 + q * 4 + r) * 66 + ct * 16 + l16] = tv;
            }
        }
        bar_lds();  // bar5

        // ---- W5: LSTM update + decay + publish (256 thr, 4 rows each) ----
        if (tid < 256) {
            int col = tid >> 2, q2 = tid & 3;
            int gcol = j * 64 + col;
            float4 cv = *(float4*)(sh_c + col * 16 + q2 * 4);
            float cc[4] = {cv.x, cv.y, cv.z, cv.w};
            u64 pk = 0;
#pragma unroll
            for (int r = 0; r < 4; ++r) {
                int row = q2 * 4 + r;
                float Ig = sh_g[(0 * 16 + row) * 66 + col];
                float Fg = sh_g[(1 * 16 + row) * 66 + col];
                float Gg = sh_g[(2 * 16 + row) * 66 + col];
                float Og = sh_g[(3 * 16 + row) * 66 + col];
                float c = Fg * cc[r] + Ig * Gg;
                cc[r] = c;
                if (t + 1 < Tz) {
                    float h = Og * tanhfast(c);
                    float hd = h * sh_gam[row * 68 + col];
                    bf16 hb = __float2bfloat16(hd);
                    sh_hbf[row * 264 + gcol] = hb;  // own slice for next step
                    pk |= (u64)(*(unsigned short*)&hb) << (16 * r);
                }
            }
            *(float4*)(sh_c + col * 16 + q2 * 4) = (float4){cc[0], cc[1], cc[2], cc[3]};
            if (t + 1 < Tz) {
                u64* pubn = pub + ((size_t)grp * 2 + ((t + 1) & 1)) * 1024;
                __hip_atomic_store(pubn + (size_t)gcol * 4 + q2, pk, __ATOMIC_RELAXED,
                                   __HIP_MEMORY_SCOPE_AGENT);
            }
        }
        if (tid < 256 && t + 1 < Tz) {
            // cross-block release: pub stores must be visible before flag.
            asm volatile("s_waitcnt vmcnt(0)" ::: "memory");
            if (lane == 0)
                __hip_atomic_store(&flags[((grp * 4 + j) * 4 + wid) * 4], (unsigned)(t + 2),
                                   __ATOMIC_RELAXED, __HIP_MEMORY_SCOPE_AGENT);
        }
        if (tid == 256 && lossStep) {
            float s0 = 0.0f;
#pragma unroll
            for (int i = 0; i < 16; ++i) s0 += sh_msum[i];
            float* lb = lossbuf + ((size_t)grp * Tz + t) * 4;
            lb[0] = s0;
            lb[1] = sh_lred[0] + sh_lred[4] + sh_lred[8] + sh_lred[12];
            lb[2] = sh_lred[1] + sh_lred[5] + sh_lred[9] + sh_lred[13];
            lb[3] = sh_lred[2] + sh_lred[6] + sh_lred[10] + sh_lred[14];
        }
        bar_lds();  // bar6 (protects all sh_* for next step)
    }
}

__global__ void rits_finalize(const float* __restrict__ lossbuf, float* __restrict__ out) {
    __shared__ float m1[Tz], m2[Tz], m3[Tz];
    int t = threadIdx.x;
    if (t < Tz) {
        float s0 = 0.0f, s1 = 0.0f, s2 = 0.0f, s3 = 0.0f;
        for (int g = 0; g < GROUPS; ++g) {
            const float* lb = lossbuf + ((size_t)g * Tz + t) * 4;
            s0 += lb[0]; s1 += lb[1]; s2 += lb[2]; s3 += lb[3];
        }
        float inv = 1.0f / (s0 + 1e-9f);
        m1[t] = s1 * inv; m2[t] = s2 * inv; m3[t] = s3 * inv;
    }
    __syncthreads();
    if (t == 0) {
        float rm = 0.0f, rl = 0.0f;
        for (int i = 0; i < Tz; ++i) {  // literal replay of reference accumulation
            rl += m1[i]; rl += m2[i]; rm += m3[i]; rl += rm;
        }
        out[(size_t)Bz * Tz * Fz] = rm / (float)Tz;
        out[(size_t)Bz * Tz * Fz + 1] = rl / (3.0f * (float)Tz);
    }
}

extern "C" void kernel_launch(void* const* d_in, const int* in_sizes, int n_in,
                              void* d_out, int out_size, void* d_ws, size_t ws_size,
                              hipStream_t stream) {
    const float* X = (const float*)d_in[0];
    const float* Mm = (const float*)d_in[1];
    const float* Dd = (const float*)d_in[2];
    const float* Wdh = (const float*)d_in[3];
    const float* b_dh = (const float*)d_in[4];
    const float* Wdx = (const float*)d_in[5];
    const float* b_dx = (const float*)d_in[6];
    const float* Whist = (const float*)d_in[7];
    const float* b_hist = (const float*)d_in[8];
    const float* Wfeat = (const float*)d_in[9];
    const float* b_feat = (const float*)d_in[10];
    const float* Wcomb = (const float*)d_in[11];
    const float* b_comb = (const float*)d_in[12];
    const float* Wih = (const float*)d_in[13];
    const float* b_ih = (const float*)d_in[14];
    const float* Whh = (const float*)d_in[15];
    const float* b_hh = (const float*)d_in[16];
    float* out = (float*)d_out;

    bf16* wsbf = (bf16*)d_ws;
    float* wdxd = (float*)((char*)d_ws + 876544);
    float* lossbuf = (float*)((char*)d_ws + 876800);
    unsigned int* flags = (unsigned int*)((char*)d_ws + 979200);
    u64* pub = (u64*)((char*)d_ws + 995584);

    rits_convert<<<1712, 256, 0, stream>>>(Wdh, Wdx, Whist, Wfeat, Wcomb, Wih, Whh, wsbf, wdxd,
                                           flags);
    rits_main<<<GROUPS * SIBS, 1024, 0, stream>>>(
        X, Mm, Dd, b_dh, b_dx, b_hist, b_feat, b_comb, b_ih, b_hh, wsbf + 0, wsbf + 16384,
        wsbf + 32768, wsbf + 36864, wsbf + 45056, wdxd, lossbuf, flags, pub, out);
    rits_finalize<<<1, 128, 0, stream>>>(lossbuf, out);
}

// Round 15
// 806.764 us; speedup vs baseline: 1.5585x; 1.5585x over previous
//
#include <hip/hip_runtime.h>
#include <hip/hip_bf16.h>

// RITS recurrent imputation, B=1024 T=100 F=64 H=256.
// FINAL (r17 verbatim, best verified: 714.8us warm, 963 -> 715 this session).
// Win chain: lossStep-gated reductions (r13, -125us) + XCD-local siblings
// (r16: j=blockIdx>>6, grp=blockIdx&63 -> pub/flag exchange in shared L2,
// FETCH 273->86MB, -22us) + LDS-only barriers (r17: s_waitcnt lgkmcnt(0) +
// s_barrier instead of __syncthreads' vmcnt(0) drain, -8us).
// Closed branches (measured, falsified): tail-consume exchange (r10: +190MB
// poll refetch), barrier-count reduction alone (r11: neutral), prefetch
// shuffling (r12: nil - barriers drained vmem anyway pre-r17), batched x4
// prefetch + reg stashing (r15: VGPR spill, unified VGPR+AGPR budget 128/wave
// is FULL at 64+64), bank remaps (r18: counter went UP - attribution wrong),
// weight hoist to registers (r19: spill again, 2.2GB scratch traffic; no
// register headroom exists at this block shape).
// Remaining structure is latency-bound (VALU 17%, MFMA 5%, HBM 4%) on the
// 6-phase serial step at 1 block/CU; the occupancy restructure that could
// attack it (512-thr blocks, 2/CU) needs 2x wfrag -> over register budget.

#define Bz 1024
#define Tz 100
#define Fz 64
#define Hz 256
#define GROUPS 64
#define SIBS 4
#define RPB 16

typedef __attribute__((ext_vector_type(8))) short short8;
typedef __attribute__((ext_vector_type(4))) float floatx4;
typedef __hip_bfloat16 bf16;
typedef unsigned long long u64;

#define MFMA16(a, b, c) __builtin_amdgcn_mfma_f32_16x16x32_bf16((a), (b), (c), 0, 0, 0)

__device__ __forceinline__ float sigmf(float x) { return 1.0f / (1.0f + __expf(-x)); }
__device__ __forceinline__ float tanhfast(float x) { return 2.0f / (1.0f + __expf(-2.0f * x)) - 1.0f; }

// LDS-only barrier: full LDS visibility (lgkmcnt 0 drain) without the
// vmcnt(0) drain __syncthreads would impose. sched_barrier(0) pins all
// memory ops on both sides (rule #18 hoisting hazard).
__device__ __forceinline__ void bar_lds() {
    __builtin_amdgcn_sched_barrier(0);
    asm volatile("s_waitcnt lgkmcnt(0)" ::: "memory");
    __builtin_amdgcn_s_barrier();
    __builtin_amdgcn_sched_barrier(0);
}

// ws layout (bytes):
//   wsbf (bf16): Wdh[256x64]@0, Whist[64x256]@16384, Wfeatm[64x64]@32768,
//     Wcomb[64x128]@36864, Wp5[12*32768]@45056 ; 438272 bf16 = 876544 B
//   @876544: wdx_diag[64] f32
//   @876800: lossbuf[64*100*4] f32 (102400 B)
//   @979200: flags[64*4*4] u32, stride 16B each (16384 B)
//   @995584: pub[64][2][256][4] u64 (1 MB)
// Wp5 flat: s*32768 + w5*2048 + g*512 + l*32 + q*8 + e ; row n=g*256+w5*16+l.

__global__ void rits_convert(const float* __restrict__ Wdh, const float* __restrict__ Wdx,
                             const float* __restrict__ Whist, const float* __restrict__ Wfeat,
                             const float* __restrict__ Wcomb, const float* __restrict__ Wih,
                             const float* __restrict__ Whh, bf16* __restrict__ wsbf,
                             float* __restrict__ wdxd, unsigned int* __restrict__ flagsArr) {
    int idx = blockIdx.x * blockDim.x + threadIdx.x;
    if (idx < 4096) flagsArr[idx] = 0u;  // zero all flag lines each launch
    if (idx < 64) wdxd[idx] = Wdx[idx * 65];  // diag of W_dx
    if (idx >= 438272) return;
    float v;
    if (idx < 16384) v = Wdh[idx];
    else if (idx < 32768) v = Whist[idx - 16384];
    else if (idx < 36864) { int i = idx - 32768; v = ((i >> 6) == (i & 63)) ? 0.0f : Wfeat[i]; }
    else if (idx < 45056) v = Wcomb[idx - 36864];
    else {
        int i = idx - 45056;
        int e = i & 7, q = (i >> 3) & 3, l = (i >> 5) & 15, g = (i >> 9) & 3, w = (i >> 11) & 15;
        int s = i >> 15;
        int n = g * 256 + w * 16 + l;
        v = (s < 4) ? Wih[n * 128 + s * 32 + q * 8 + e] : Whh[n * 256 + (s - 4) * 32 + q * 8 + e];
    }
    wsbf[idx] = __float2bfloat16(v);
}

__global__ __launch_bounds__(1024, 4) void rits_main(
    const float* __restrict__ X, const float* __restrict__ Mm, const float* __restrict__ Dd,
    const float* __restrict__ b_dh, const float* __restrict__ b_dx,
    const float* __restrict__ b_hist, const float* __restrict__ b_feat,
    const float* __restrict__ b_comb, const float* __restrict__ b_ih,
    const float* __restrict__ b_hh,
    const bf16* __restrict__ Wdh, const bf16* __restrict__ Whist,
    const bf16* __restrict__ Wfeatm, const bf16* __restrict__ Wcomb,
    const bf16* __restrict__ Wp5,
    const float* __restrict__ wdxd, float* __restrict__ lossbuf,
    unsigned int* __restrict__ flags, u64* __restrict__ pub, float* __restrict__ out) {
    // ---- LDS (~130 KB -> 1 block/CU) ----
    __shared__ __align__(16) bf16 lw_hist[64 * 264];
    __shared__ __align__(16) bf16 lw_comb[64 * 136];
    __shared__ __align__(16) bf16 lw_feat[64 * 72];
    __shared__ __align__(16) bf16 lw_dh[64 * 72];
    __shared__ __align__(16) bf16 sh_hbf[RPB * 264];   // full decayed h (bf16)
    __shared__ __align__(16) float sh_x[RPB * 64];
    __shared__ __align__(16) float sh_m[RPB * 64];
    __shared__ __align__(16) bf16 sh_dbf2[RPB * 72];   // d(t+1), staged in W2
    __shared__ __align__(16) bf16 sh_xcbf[RPB * 72];
    __shared__ __align__(16) bf16 sh_gmbf[RPB * 136];
    __shared__ __align__(16) bf16 sh_inbf[RPB * 136];
    __shared__ __align__(16) float sh_alpha[RPB * 68];
    __shared__ __align__(16) float sh_gam[RPB * 68];   // gamma_h(d_{t+1}), own cols
    __shared__ __align__(16) float sh_g[4 * 16 * 66];  // post-nonlin gates
    __shared__ __align__(16) float sh_c[64 * 16];      // c state, col-major [col][row]
    __shared__ float sh_lred[16];
    __shared__ float sh_msum[16];

    const int tid = threadIdx.x;
    const int lane = tid & 63;
    const int wid = tid >> 6;   // 0..15
    const int l16 = lane & 15;
    const int q = lane >> 4;    // 0..3
    const int j = blockIdx.x >> 6;    // sibling: owns H cols [64j, 64j+64)
    const int grp = blockIdx.x & 63;  // siblings {g,g+64,g+128,g+192} -> same XCD
    const int b0 = grp * RPB;

    // ---- one-time LDS copy-in of small weights; state init ----
    for (int i = tid; i < 64 * 256; i += 1024) lw_hist[(i >> 8) * 264 + (i & 255)] = Whist[i];
    for (int i = tid; i < 64 * 128; i += 1024) lw_comb[(i >> 7) * 136 + (i & 127)] = Wcomb[i];
    for (int i = tid; i < 64 * 64; i += 1024) {
        lw_feat[(i >> 6) * 72 + (i & 63)] = Wfeatm[i];
        lw_dh[(i >> 6) * 72 + (i & 63)] = Wdh[(j * 64 + (i >> 6)) * 64 + (i & 63)];
    }
    for (int i = tid; i < 64 * 16; i += 1024) sh_c[i] = 0.0f;
    for (int i = tid; i < RPB * 264; i += 1024) sh_hbf[i] = (bf16)0.0f;

    // ---- P5 gate-weight fragments: PERMANENT register residency ----
    const int gate = wid >> 2;  // 0..3 (i,f,g,o)
    const int ct = wid & 3;     // col-tile within sibling slice
    const int nrow = gate * 256 + j * 64 + ct * 16 + l16;
    short8 wfrag[12];
#pragma unroll
    for (int s = 0; s < 12; ++s)
        wfrag[s] = *(const short8*)(Wp5 + (size_t)s * 32768 + (j * 4 + ct) * 2048 + gate * 512 +
                                    l16 * 32 + q * 8);
    const float bgate = b_ih[nrow] + b_hh[nrow];

    // ---- step-invariant scalars (per-role) ----
    const float wdxf = wdxd[lane];
    const float bdxf = b_dx[lane];
    const int ca = wid * 16 + l16;          // alpha col (w0-3)
    const int colF = (wid - 4) * 16 + l16;  // F col (w4-7)
    const int colg = (wid - 8) * 16 + l16;  // gamma2 local col (w8-11)
    float bc2 = 0.f, bhl = 0.f, bft = 0.f, bdl = 0.f;
    if (wid < 4) bc2 = b_comb[ca];
    else if (wid < 8) { bhl = b_hist[colF]; bft = b_feat[colF]; }
    else if (wid < 12) bdl = b_dh[j * 64 + colg];

    const size_t g0 = (size_t)(b0 + wid) * Tz * Fz + lane;
    float xv = X[g0], mv = Mm[g0], dv = Dd[g0];

    __syncthreads();  // full barrier: LDS init + weight staging complete

    // ---- initial publish: zeros for t=0 (h=0 -> decayed h=0), flags=1 ----
    {
        u64* pub0 = pub + (size_t)grp * 2 * 1024;
        if (tid < 256) {
            int col = tid >> 2, qq = tid & 3;
            __hip_atomic_store(pub0 + (size_t)(j * 64 + col) * 4 + qq, 0ull, __ATOMIC_RELAXED,
                               __HIP_MEMORY_SCOPE_AGENT);
        }
        asm volatile("s_waitcnt vmcnt(0)" ::: "memory");
        if (tid < 256 && lane == 0)
            __hip_atomic_store(&flags[((grp * 4 + j) * 4 + wid) * 4], 1u, __ATOMIC_RELAXED,
                               __HIP_MEMORY_SCOPE_AGENT);
    }

    for (int t = 0; t < Tz; ++t) {
        const bool lossStep = ((t & 3) == j);
        u64* pubt = pub + ((size_t)grp * 2 + (t & 1)) * 1024;

        // ---- W0: stage x,m; gamma_x; msum; issue t+1 prefetch; poll ----
        {
            const int row = wid, f = lane;
            sh_x[row * 64 + f] = xv;
            sh_m[row * 64 + f] = mv;
            float gx = __expf(-fmaxf(dv * wdxf + bdxf, 0.0f));
            sh_gmbf[row * 136 + f] = __float2bfloat16(gx);
            bf16 mb = __float2bfloat16(mv);
            sh_gmbf[row * 136 + 64 + f] = mb;
            sh_inbf[row * 136 + 64 + f] = mb;
            if (lossStep) {  // msum only computed on the step this block consumes it
                float v0 = mv;
#pragma unroll
                for (int off = 32; off; off >>= 1) v0 += __shfl_xor(v0, off, 64);
                if (lane == 0) sh_msum[wid] = v0;
            }
        }
        if (t + 1 < Tz) {  // t+1 loads issue here; with LDS-only barriers they
            size_t g = g0 + (size_t)(t + 1) * Fz;  // float to their consumers
            xv = X[g]; mv = Mm[g]; dv = Dd[g];
        }
        if (tid < 12) {  // flags were set during remote step t-1 tail -> ~1-shot
            int sidx = tid >> 2;
            int sib = sidx + (sidx >= j);
            int w = tid & 3;
            const unsigned target = (unsigned)(t + 1);
            unsigned it = 0;
            while (__hip_atomic_load(&flags[((grp * 4 + sib) * 4 + w) * 4], __ATOMIC_RELAXED,
                                     __HIP_MEMORY_SCOPE_AGENT) < target) {
                __builtin_amdgcn_s_sleep(1);
                if (++it > (1u << 22)) break;  // liveness escape
            }
        }
        bar_lds();  // bar1

        // ---- W1: readback remote decayed-h slices -> sh_hbf ----
        if (tid < 768) {
            int sidx = tid >> 8;
            int sib = sidx + (sidx >= j);
            int c = sib * 64 + ((tid >> 2) & 63);
            int qq = tid & 3;
            u64 v = __hip_atomic_load(pubt + (size_t)c * 4 + qq, __ATOMIC_RELAXED,
                                      __HIP_MEMORY_SCOPE_AGENT);
            unsigned short* hb = (unsigned short*)sh_hbf;
#pragma unroll
            for (int r = 0; r < 4; ++r) hb[(qq * 4 + r) * 264 + c] = (unsigned short)(v >> (16 * r));
        }
        bar_lds();  // bar2

        // ---- W2: P2+xc (w4-7) | alpha (w0-3) | P5 s2-11 (all but w4-7) ----
        floatx4 acc5 = {0.f, 0.f, 0.f, 0.f};
        float xh[4];
        float l1 = 0.f, l2 = 0.f, l3 = 0.f;
        if (wid >= 4 && wid < 8) {
            floatx4 acc = {0.f, 0.f, 0.f, 0.f};
#pragma unroll
            for (int kb = 0; kb < 8; ++kb) {
                short8 a = *(const short8*)(sh_hbf + l16 * 264 + kb * 32 + q * 8);
                short8 b = *(const short8*)(lw_hist + colF * 264 + kb * 32 + q * 8);
                acc = MFMA16(a, b, acc);
            }
#pragma unroll
            for (int r = 0; r < 4; ++r) {
                int row = q * 4 + r;
                xh[r] = acc[r] + bhl;
                float xx = sh_x[row * 64 + colF], mm = sh_m[row * 64 + colF];
                l1 += fabsf(xh[r] - xx) * mm;
                float xc = mm * xx + (1.0f - mm) * xh[r];
                sh_xcbf[row * 72 + colF] = __float2bfloat16(xc);
            }
        } else {
            if (wid < 4) {
                floatx4 acca = {0.f, 0.f, 0.f, 0.f};
#pragma unroll
                for (int kb = 0; kb < 4; ++kb) {
                    short8 a = *(const short8*)(sh_gmbf + l16 * 136 + kb * 32 + q * 8);
                    short8 b = *(const short8*)(lw_comb + ca * 136 + kb * 32 + q * 8);
                    acca = MFMA16(a, b, acca);
                }
#pragma unroll
                for (int r = 0; r < 4; ++r) sh_alpha[(q * 4 + r) * 68 + ca] = sigmf(acca[r] + bc2);
            }
#pragma unroll
            for (int s = 2; s < 4; ++s) {
                short8 a = *(const short8*)(sh_inbf + l16 * 136 + s * 32 + q * 8);
                acc5 = MFMA16(a, wfrag[s], acc5);
            }
#pragma unroll
            for (int s = 4; s < 12; ++s) {
                short8 a = *(const short8*)(sh_hbf + l16 * 264 + (s - 4) * 32 + q * 8);
                acc5 = MFMA16(a, wfrag[s], acc5);
            }
        }
        if (t + 1 < Tz) sh_dbf2[wid * 72 + lane] = __float2bfloat16(dv);
        bar_lds();  // bar3

        // ---- W3: P34 epilogue (w4-7) | gamma_h(d_{t+1}) (w8-11) ----
        if (wid >= 4 && wid < 8) {
            floatx4 accz = {0.f, 0.f, 0.f, 0.f};
            {
                short8 a = *(const short8*)(sh_xcbf + l16 * 72 + q * 8);
                accz = MFMA16(a, *(const short8*)(lw_feat + colF * 72 + q * 8), accz);
                a = *(const short8*)(sh_xcbf + l16 * 72 + 32 + q * 8);
                accz = MFMA16(a, *(const short8*)(lw_feat + colF * 72 + 32 + q * 8), accz);
            }
#pragma unroll
            for (int r = 0; r < 4; ++r) {
                int row = q * 4 + r;
                float xx = sh_x[row * 64 + colF], mm = sh_m[row * 64 + colF];
                float z = accz[r] + bft;
                l2 += fabsf(z - xx) * mm;
                float al = sh_alpha[row * 68 + colF];
                float ch = al * z + (1.0f - al) * xh[r];
                l3 += fabsf(ch - xx) * mm;
                float imp = mm * xx + (1.0f - mm) * ch;  // == c_c
                if (wid - 4 == j) out[((size_t)(b0 + row) * Tz + t) * Fz + colF] = imp;
                sh_inbf[row * 136 + colF] = __float2bfloat16(imp);
            }
            if (lossStep) {  // reduce only on the step this block publishes loss
                float v1 = l1, v2 = l2, v3 = l3;
#pragma unroll
                for (int off = 32; off; off >>= 1) {
                    v1 += __shfl_xor(v1, off, 64);
                    v2 += __shfl_xor(v2, off, 64);
                    v3 += __shfl_xor(v3, off, 64);
                }
                if (lane == 0) {
                    sh_lred[(wid - 4) * 4 + 0] = v1;
                    sh_lred[(wid - 4) * 4 + 1] = v2;
                    sh_lred[(wid - 4) * 4 + 2] = v3;
                }
            }
        } else if (wid >= 8 && wid < 12 && t + 1 < Tz) {
            short8 a0 = *(const short8*)(sh_dbf2 + l16 * 72 + q * 8);
            short8 a1 = *(const short8*)(sh_dbf2 + l16 * 72 + 32 + q * 8);
            short8 w0 = *(const short8*)(lw_dh + colg * 72 + q * 8);
            short8 w1 = *(const short8*)(lw_dh + colg * 72 + 32 + q * 8);
            floatx4 acc = {0.f, 0.f, 0.f, 0.f};
            acc = MFMA16(a0, w0, acc);
            acc = MFMA16(a1, w1, acc);
#pragma unroll
            for (int r = 0; r < 4; ++r)
                sh_gam[(q * 4 + r) * 68 + colg] = __expf(-fmaxf(acc[r] + bdl, 0.0f));
        }
        bar_lds();  // bar4

        // ---- W4: all 16 waves finish gates (s0,1 = c_c slots) + nonlin ----
        {
#pragma unroll
            for (int s = 0; s < 2; ++s) {
                short8 a = *(const short8*)(sh_inbf + l16 * 136 + s * 32 + q * 8);
                acc5 = MFMA16(a, wfrag[s], acc5);
            }
#pragma unroll
            for (int r = 0; r < 4; ++r) {
                float v = acc5[r] + bgate;
                float tv = (gate == 2) ? tanhfast(v) : sigmf(v);
                sh_g[(gate * 16 + q * 4 + r) * 66 + ct * 16 + l16] = tv;
            }
        }
        bar_lds();  // bar5

        // ---- W5: LSTM update + decay + publish (256 thr, 4 rows each) ----
        if (tid < 256) {
            int col = tid >> 2, q2 = tid & 3;
            int gcol = j * 64 + col;
            float4 cv = *(float4*)(sh_c + col * 16 + q2 * 4);
            float cc[4] = {cv.x, cv.y, cv.z, cv.w};
            u64 pk = 0;
#pragma unroll
            for (int r = 0; r < 4; ++r) {
                int row = q2 * 4 + r;
                float Ig = sh_g[(0 * 16 + row) * 66 + col];
                float Fg = sh_g[(1 * 16 + row) * 66 + col];
                float Gg = sh_g[(2 * 16 + row) * 66 + col];
                float Og = sh_g[(3 * 16 + row) * 66 + col];
                float c = Fg * cc[r] + Ig * Gg;
                cc[r] = c;
                if (t + 1 < Tz) {
                    float h = Og * tanhfast(c);
                    float hd = h * sh_gam[row * 68 + col];
                    bf16 hb = __float2bfloat16(hd);
                    sh_hbf[row * 264 + gcol] = hb;  // own slice for next step
                    pk |= (u64)(*(unsigned short*)&hb) << (16 * r);
                }
            }
            *(float4*)(sh_c + col * 16 + q2 * 4) = (float4){cc[0], cc[1], cc[2], cc[3]};
            if (t + 1 < Tz) {
                u64* pubn = pub + ((size_t)grp * 2 + ((t + 1) & 1)) * 1024;
                __hip_atomic_store(pubn + (size_t)gcol * 4 + q2, pk, __ATOMIC_RELAXED,
                                   __HIP_MEMORY_SCOPE_AGENT);
            }
        }
        if (tid < 256 && t + 1 < Tz) {
            // cross-block release: pub stores must be visible before flag.
            asm volatile("s_waitcnt vmcnt(0)" ::: "memory");
            if (lane == 0)
                __hip_atomic_store(&flags[((grp * 4 + j) * 4 + wid) * 4], (unsigned)(t + 2),
                                   __ATOMIC_RELAXED, __HIP_MEMORY_SCOPE_AGENT);
        }
        if (tid == 256 && lossStep) {
            float s0 = 0.0f;
#pragma unroll
            for (int i = 0; i < 16; ++i) s0 += sh_msum[i];
            float* lb = lossbuf + ((size_t)grp * Tz + t) * 4;
            lb[0] = s0;
            lb[1] = sh_lred[0] + sh_lred[4] + sh_lred[8] + sh_lred[12];
            lb[2] = sh_lred[1] + sh_lred[5] + sh_lred[9] + sh_lred[13];
            lb[3] = sh_lred[2] + sh_lred[6] + sh_lred[10] + sh_lred[14];
        }
        bar_lds();  // bar6 (protects all sh_* for next step)
    }
}

__global__ void rits_finalize(const float* __restrict__ lossbuf, float* __restrict__ out) {
    __shared__ float m1[Tz], m2[Tz], m3[Tz];
    int t = threadIdx.x;
    if (t < Tz) {
        float s0 = 0.0f, s1 = 0.0f, s2 = 0.0f, s3 = 0.0f;
        for (int g = 0; g < GROUPS; ++g) {
            const float* lb = lossbuf + ((size_t)g * Tz + t) * 4;
            s0 += lb[0]; s1 += lb[1]; s2 += lb[2]; s3 += lb[3];
        }
        float inv = 1.0f / (s0 + 1e-9f);
        m1[t] = s1 * inv; m2[t] = s2 * inv; m3[t] = s3 * inv;
    }
    __syncthreads();
    if (t == 0) {
        float rm = 0.0f, rl = 0.0f;
        for (int i = 0; i < Tz; ++i) {  // literal replay of reference accumulation
            rl += m1[i]; rl += m2[i]; rm += m3[i]; rl += rm;
        }
        out[(size_t)Bz * Tz * Fz] = rm / (float)Tz;
        out[(size_t)Bz * Tz * Fz + 1] = rl / (3.0f * (float)Tz);
    }
}

extern "C" void kernel_launch(void* const* d_in, const int* in_sizes, int n_in,
                              void* d_out, int out_size, void* d_ws, size_t ws_size,
                              hipStream_t stream) {
    const float* X = (const float*)d_in[0];
    const float* Mm = (const float*)d_in[1];
    const float* Dd = (const float*)d_in[2];
    const float* Wdh = (const float*)d_in[3];
    const float* b_dh = (const float*)d_in[4];
    const float* Wdx = (const float*)d_in[5];
    const float* b_dx = (const float*)d_in[6];
    const float* Whist = (const float*)d_in[7];
    const float* b_hist = (const float*)d_in[8];
    const float* Wfeat = (const float*)d_in[9];
    const float* b_feat = (const float*)d_in[10];
    const float* Wcomb = (const float*)d_in[11];
    const float* b_comb = (const float*)d_in[12];
    const float* Wih = (const float*)d_in[13];
    const float* b_ih = (const float*)d_in[14];
    const float* Whh = (const float*)d_in[15];
    const float* b_hh = (const float*)d_in[16];
    float* out = (float*)d_out;

    bf16* wsbf = (bf16*)d_ws;
    float* wdxd = (float*)((char*)d_ws + 876544);
    float* lossbuf = (float*)((char*)d_ws + 876800);
    unsigned int* flags = (unsigned int*)((char*)d_ws + 979200);
    u64* pub = (u64*)((char*)d_ws + 995584);

    rits_convert<<<1712, 256, 0, stream>>>(Wdh, Wdx, Whist, Wfeat, Wcomb, Wih, Whh, wsbf, wdxd,
                                           flags);
    rits_main<<<GROUPS * SIBS, 1024, 0, stream>>>(
        X, Mm, Dd, b_dh, b_dx, b_hist, b_feat, b_comb, b_ih, b_hh, wsbf + 0, wsbf + 16384,
        wsbf + 32768, wsbf + 36864, wsbf + 45056, wdxd, lossbuf, flags, pub, out);
    rits_finalize<<<1, 128, 0, stream>>>(lossbuf, out);
}